// Round 3
// baseline (482.874 us; speedup 1.0000x reference)
//
#include <hip/hip_runtime.h>
#include <hip/hip_bf16.h>

typedef __attribute__((ext_vector_type(8))) short bf16x8;
typedef __attribute__((ext_vector_type(4))) float f32x4;

#define N_OBJ 1024
#define N_REL 1024
#define NB 32
#define D 512
#define VOCAB 2048
#define M_ROWS (NB * N_REL)          // 32768
#define PRE_BLK (VOCAB * D)          // 1048576 floats per PRE block
#define WT_BLK (D * D)               // 262144 elems per transposed weight block

__device__ __forceinline__ ushort f2bf(float f) {
    union { float f; unsigned u; } v; v.f = f;
    unsigned u = v.u;
    unsigned r = (u + 0x7FFFu + ((u >> 16) & 1u)) >> 16;
    return (ushort)r;
}

// global -> LDS async 16B copy (m97 pattern; dest is wave-uniform base + lane*16,
// our per-thread dest tid*16 is exactly lane-linear so layout stays contiguous)
__device__ __forceinline__ void gload16(const ushort* g, const ushort* l) {
    __builtin_amdgcn_global_load_lds(
        (const __attribute__((address_space(1))) void*)(unsigned long long)(const void*)g,
        (__attribute__((address_space(3))) void*)(unsigned)(unsigned long long)(const void*)l,
        16, 0, 0);
}

// ---------------- K0a: emb_table f32 -> bf16 (float4) ----------------
__global__ void k_cvt_emb(const float* __restrict__ E, ushort* __restrict__ EB) {
    int i = blockIdx.x * 256 + threadIdx.x;   // over 262144 float4 groups
    float4 v = ((const float4*)E)[i];
    ushort4 o; o.x = f2bf(v.x); o.y = f2bf(v.y); o.z = f2bf(v.z); o.w = f2bf(v.w);
    ((ushort4*)EB)[i] = o;
}

// ---------------- K0b: transpose weight 512x512 blocks to N x K bf16 ----------------
// WT block order: 0,1,2 = W_sbj k-blocks; 3,4,5 = W_obj; 6,7,8 = W_rel; 9 = W_o; 10,11 = W_a
__global__ void k_transpose_w(const float* __restrict__ Wsbj, const float* __restrict__ Wobj,
                              const float* __restrict__ Wrel, const float* __restrict__ Wo,
                              const float* __restrict__ Wa, ushort* __restrict__ WT) {
    __shared__ float s[32][33];
    int q = blockIdx.z;
    const float* src; int ro;
    if (q < 3)       { src = Wsbj; ro = q * 512; }
    else if (q < 6)  { src = Wobj; ro = (q - 3) * 512; }
    else if (q < 9)  { src = Wrel; ro = (q - 6) * 512; }
    else if (q == 9) { src = Wo;   ro = 0; }
    else             { src = Wa;   ro = (q - 10) * 512; }
    int tx = threadIdx.x, ty = threadIdx.y;        // 32 x 8
    int kbase = blockIdx.y * 32, nbase = blockIdx.x * 32;
#pragma unroll
    for (int i = 0; i < 4; i++) {
        int k = kbase + ty + i * 8;
        s[ty + i * 8][tx] = src[(size_t)(ro + k) * 512 + nbase + tx];
    }
    __syncthreads();
    ushort* dst = WT + (size_t)q * WT_BLK;
#pragma unroll
    for (int i = 0; i < 4; i++) {
        int n = nbase + ty + i * 8;
        dst[(size_t)n * 512 + kbase + tx] = f2bf(s[tx][ty + i * 8]);
    }
}

// ---------------- GEMM: 128x128 tile, BK=64, global_load_lds, bf16 MFMA 16x16x32 ----
// MODE 0: PRE = EB @ WT[q]        grid (16 Mtile, 4 Ntile, 9 q),  K=512, lda=512
// MODE 1: obj_f = sbjf @ Wobj0    grid (4 Ntile, 256 Mtile),      K=512, lda=1024
//         epilogue: + PRE3[io] + PRE4[rid] + b_obj, relu, mask; featbuf hi-half + node atomics
// MODE 2: rel_f = [sbjf|objf] @ [Wrel0;Wrel1]  grid (4, 256),     K=1024, lda=1024
//         epilogue: + PRE5[rid] + b_rel, relu, mask -> out0 (f32)
template <int MODE>
__global__ __launch_bounds__(256)
void k_gemm(const ushort* __restrict__ A, const ushort* __restrict__ WT,
            float* __restrict__ PRE,
            const int* __restrict__ ssg_rel, const int* __restrict__ ssg_obj,
            const float* __restrict__ bias,
            ushort* __restrict__ featbuf,
            float* __restrict__ node, float* __restrict__ out0) {
    __shared__ __attribute__((aligned(16))) ushort sA[128 * 64];
    __shared__ __attribute__((aligned(16))) ushort sB[128 * 64];

    const int tid = threadIdx.x;
    const int mt = (MODE == 0) ? blockIdx.x : blockIdx.y;
    const int nt = (MODE == 0) ? blockIdx.y : blockIdx.x;
    const int m0 = mt * 128;
    constexpr int LDA = (MODE == 0) ? 512 : 1024;
    constexpr int KTOT = (MODE == 2) ? 1024 : 512;

    const ushort* BT0;        // B block for k in [0,512)
    const ushort* BT1 = nullptr;  // B block for k in [512,1024) (MODE 2)
    float* PREq = nullptr;
    if (MODE == 0) {
        const int wtq[9] = {0, 1, 2, 4, 5, 8, 9, 10, 11};
        int q = blockIdx.z;
        BT0 = WT + (size_t)wtq[q] * WT_BLK + (size_t)nt * 128 * 512;
        PREq = PRE + (size_t)q * PRE_BLK;
    } else if (MODE == 1) {
        BT0 = WT + (size_t)3 * WT_BLK + (size_t)nt * 128 * 512;
    } else {
        BT0 = WT + (size_t)6 * WT_BLK + (size_t)nt * 128 * 512;
        BT1 = WT + (size_t)7 * WT_BLK + (size_t)nt * 128 * 512;
    }

    const int wave = tid >> 6;
    const int wm = wave >> 1, wn = wave & 1;
    const int lr = tid & 15, lk = (tid & 63) >> 4;

    f32x4 acc[4][4];
#pragma unroll
    for (int mi = 0; mi < 4; mi++)
#pragma unroll
        for (int ni = 0; ni < 4; ni++)
            acc[mi][ni] = (f32x4){0.f, 0.f, 0.f, 0.f};

    const ushort* Ag = A + (size_t)m0 * LDA;
    const int srow = tid >> 3;            // 0..31 (row within 32-row staging group)
    const int scol = (tid & 7) * 8;       // 0..56

    for (int k0 = 0; k0 < KTOT; k0 += 64) {
        const ushort* As = Ag + (size_t)srow * LDA + k0 + scol;
        const ushort* Bbase = (MODE == 2 && k0 >= 512) ? (BT1 + (k0 - 512)) : (BT0 + k0);
        const ushort* Bs = Bbase + (size_t)srow * 512 + scol;
#pragma unroll
        for (int i = 0; i < 4; i++)
            gload16(As + (size_t)i * 32 * LDA, &sA[i * 2048 + tid * 8]);
#pragma unroll
        for (int i = 0; i < 4; i++)
            gload16(Bs + (size_t)i * 32 * 512, &sB[i * 2048 + tid * 8]);
        __syncthreads();    // compiler drains vmcnt before barrier (m97 semantics)
#pragma unroll
        for (int ks = 0; ks < 2; ks++) {
            bf16x8 af[4], bfr[4];
#pragma unroll
            for (int mi = 0; mi < 4; mi++)
                af[mi] = *(const bf16x8*)&sA[(wm * 64 + mi * 16 + lr) * 64 + ks * 32 + lk * 8];
#pragma unroll
            for (int ni = 0; ni < 4; ni++)
                bfr[ni] = *(const bf16x8*)&sB[(wn * 64 + ni * 16 + lr) * 64 + ks * 32 + lk * 8];
#pragma unroll
            for (int mi = 0; mi < 4; mi++)
#pragma unroll
                for (int ni = 0; ni < 4; ni++)
                    acc[mi][ni] = __builtin_amdgcn_mfma_f32_16x16x32_bf16(af[mi], bfr[ni], acc[mi][ni], 0, 0, 0);
        }
        __syncthreads();
    }

    // ---- epilogue ----
    int* sIo  = (int*)sA;          // overlay (main loop done, post-barrier)
    int* sRid = sIo + 128;
    int* sOid = sRid + 128;
    if (MODE == 1 || MODE == 2) {
        if (tid < 128) {
            int R = m0 + tid;
            int oid = ssg_rel[R * 3 + 1];
            int rid = ssg_rel[R * 3 + 2];
            sOid[tid] = oid;
            sRid[tid] = rid;
            if (MODE == 1) sIo[tid] = ssg_obj[(R & ~(N_OBJ - 1)) + oid];
        }
        __syncthreads();
    }

#pragma unroll
    for (int mi = 0; mi < 4; mi++) {
#pragma unroll
        for (int ni = 0; ni < 4; ni++) {
            int c = wn * 64 + ni * 16 + lr;   // local col 0..127
            int ch = nt * 128 + c;
#pragma unroll
            for (int j = 0; j < 4; j++) {
                int rl = wm * 64 + mi * 16 + lk * 4 + j;
                int R = m0 + rl;
                float v = acc[mi][ni][j];
                if (MODE == 0) {
                    PREq[(size_t)R * 512 + ch] = v;
                } else if (MODE == 1) {
                    int rid = sRid[rl];
                    int io = sIo[rl];
                    float t = v + PRE[(size_t)3 * PRE_BLK + (size_t)io * 512 + ch]
                                + PRE[(size_t)4 * PRE_BLK + (size_t)rid * 512 + ch]
                                + bias[ch];
                    t = fmaxf(t, 0.f);
                    if (rid == 1) t = 0.f;
                    featbuf[(size_t)R * 1024 + 512 + ch] = f2bf(t);
                    if (t != 0.f) {
                        int oid = sOid[rl];
                        atomicAdd(&node[(size_t)((R & ~(N_OBJ - 1)) + oid) * 512 + ch], t);
                    }
                } else {  // MODE 2
                    int rid = sRid[rl];
                    float t = v + PRE[(size_t)5 * PRE_BLK + (size_t)rid * 512 + ch]
                                + bias[ch];
                    t = fmaxf(t, 0.f);
                    if (rid == 1) t = 0.f;
                    int b = R >> 10, rr = R & (N_REL - 1);
                    out0[((size_t)(b * 3072 + 1024 + rr)) * 512 + ch] = t;
                }
            }
        }
    }
}

// ---------------- node init: node = masked relu(PRE6[ssg_obj] + b_o)  (float4) ------
__global__ void k_node_init(const int* __restrict__ ssg_obj, const float* __restrict__ PRE,
                            const float* __restrict__ b_o, float* __restrict__ node) {
    int Ro = blockIdx.x * 2 + (threadIdx.x >> 7);
    int c4 = threadIdx.x & 127;
    int iv = ssg_obj[Ro];
    float4 q = ((const float4*)(PRE + (size_t)6 * PRE_BLK + (size_t)iv * 512))[c4];
    float4 b = ((const float4*)b_o)[c4];
    float4 r;
    r.x = fmaxf(q.x + b.x, 0.f); r.y = fmaxf(q.y + b.y, 0.f);
    r.z = fmaxf(q.z + b.z, 0.f); r.w = fmaxf(q.w + b.w, 0.f);
    if (iv == 1) { r.x = r.y = r.z = r.w = 0.f; }
    ((float4*)node)[(size_t)Ro * 128 + c4] = r;
}

// ---------------- sbj_f: table lookup layer + scatter into node (float4) ----------
__global__ void k_sbj(const int* __restrict__ ssg_rel, const int* __restrict__ ssg_obj,
                      const float* __restrict__ PRE, const float* __restrict__ b_sbj,
                      ushort* __restrict__ featbuf, float* __restrict__ node) {
    int R = blockIdx.x * 2 + (threadIdx.x >> 7);
    int c4 = threadIdx.x & 127;
    int sid = ssg_rel[R * 3 + 0];
    int oid = ssg_rel[R * 3 + 1];
    int rid = ssg_rel[R * 3 + 2];
    int bb = R & ~(N_OBJ - 1);
    int is_ = ssg_obj[bb + sid];
    int io  = ssg_obj[bb + oid];
    float4 p1 = ((const float4*)(PRE + (size_t)is_ * 512))[c4];
    float4 p2 = ((const float4*)(PRE + (size_t)1 * PRE_BLK + (size_t)io * 512))[c4];
    float4 p3 = ((const float4*)(PRE + (size_t)2 * PRE_BLK + (size_t)rid * 512))[c4];
    float4 b  = ((const float4*)b_sbj)[c4];
    float4 v;
    v.x = fmaxf(p1.x + p2.x + p3.x + b.x, 0.f);
    v.y = fmaxf(p1.y + p2.y + p3.y + b.y, 0.f);
    v.z = fmaxf(p1.z + p2.z + p3.z + b.z, 0.f);
    v.w = fmaxf(p1.w + p2.w + p3.w + b.w, 0.f);
    if (rid == 1) { v.x = v.y = v.z = v.w = 0.f; }
    ushort4 o; o.x = f2bf(v.x); o.y = f2bf(v.y); o.z = f2bf(v.z); o.w = f2bf(v.w);
    *(ushort4*)&featbuf[(size_t)R * 1024 + c4 * 4] = o;
    float* np = &node[(size_t)(bb + sid) * 512 + c4 * 4];
    if (v.x != 0.f) atomicAdd(np + 0, v.x);
    if (v.y != 0.f) atomicAdd(np + 1, v.y);
    if (v.z != 0.f) atomicAdd(np + 2, v.z);
    if (v.w != 0.f) atomicAdd(np + 3, v.w);
}

// ---------------- node -> out (rel_object_feat = node / 2048) (float4) -------------
__global__ void k_node_out(const float* __restrict__ node, float* __restrict__ out0) {
    int i4 = blockIdx.x * 256 + threadIdx.x;   // over 4.19M float4
    int Ro = i4 >> 7, c4 = i4 & 127;
    int b = Ro >> 10, o = Ro & (N_OBJ - 1);
    float4 v = ((const float4*)node)[(size_t)i4];
    v.x *= (1.0f / 2048.0f); v.y *= (1.0f / 2048.0f);
    v.z *= (1.0f / 2048.0f); v.w *= (1.0f / 2048.0f);
    ((float4*)out0)[((size_t)(b * 3072 + o)) * 128 + c4] = v;
}

// ---------------- att features (float4) ----------------
__global__ void k_att(const int* __restrict__ ssg_obj, const int* __restrict__ ssg_att,
                      const float* __restrict__ PRE, const float* __restrict__ b_a,
                      float* __restrict__ out0) {
    int Ro = blockIdx.x * 2 + (threadIdx.x >> 7);
    int c4 = threadIdx.x & 127;
    int iv = ssg_obj[Ro];
    int j0 = ssg_att[Ro * 4 + 0], j1 = ssg_att[Ro * 4 + 1];
    int j2 = ssg_att[Ro * 4 + 2], j3 = ssg_att[Ro * 4 + 3];
    const float4* A2 = (const float4*)(PRE + (size_t)8 * PRE_BLK);
    float4 a1 = ((const float4*)(PRE + (size_t)7 * PRE_BLK + (size_t)iv * 512))[c4];
    float4 ba = ((const float4*)b_a)[c4];
    float4 base;
    base.x = a1.x + ba.x; base.y = a1.y + ba.y; base.z = a1.z + ba.z; base.w = a1.w + ba.w;
    int cnt = (j0 != 1) + (j1 != 1) + (j2 != 1) + (j3 != 1);
    float inv = cnt ? 1.0f / (float)cnt : 0.f;
    float4 s = {0.f, 0.f, 0.f, 0.f};
#define ACC_ATT(J) if ((J) != 1) { \
        float4 a2 = A2[(size_t)(J) * 128 + c4]; \
        s.x += fmaxf(base.x + a2.x, 0.f); s.y += fmaxf(base.y + a2.y, 0.f); \
        s.z += fmaxf(base.z + a2.z, 0.f); s.w += fmaxf(base.w + a2.w, 0.f); }
    ACC_ATT(j0) ACC_ATT(j1) ACC_ATT(j2) ACC_ATT(j3)
#undef ACC_ATT
    s.x *= inv; s.y *= inv; s.z *= inv; s.w *= inv;
    int b = Ro >> 10, o = Ro & (N_OBJ - 1);
    ((float4*)out0)[((size_t)(b * 3072 + 2048 + o)) * 128 + c4] = s;
}

// ---------------- masks ----------------
__global__ void k_mask(const int* __restrict__ ssg_rel, const int* __restrict__ ssg_obj,
                       const int* __restrict__ ssg_att, float* __restrict__ out1) {
    int i = blockIdx.x * 256 + threadIdx.x;
    if (i >= NB * 3072) return;
    int b = i / 3072, j = i % 3072;
    bool m;
    if (j < 1024) m = (ssg_obj[b * 1024 + j] == 1);
    else if (j < 2048) m = (ssg_rel[(b * 1024 + (j - 1024)) * 3 + 2] == 1);
    else {
        const int* p = ssg_att + (size_t)(b * 1024 + (j - 2048)) * 4;
        m = (p[0] == 1) && (p[1] == 1) && (p[2] == 1) && (p[3] == 1);
    }
    out1[i] = m ? 1.0f : 0.0f;
}

extern "C" void kernel_launch(void* const* d_in, const int* in_sizes, int n_in,
                              void* d_out, int out_size, void* d_ws, size_t ws_size,
                              hipStream_t stream) {
    const int*   ssg_rel = (const int*)d_in[0];
    const int*   ssg_obj = (const int*)d_in[1];
    const int*   ssg_att = (const int*)d_in[2];
    const float* emb     = (const float*)d_in[3];
    const float* Wsbj    = (const float*)d_in[4];
    const float* bsbj    = (const float*)d_in[5];
    const float* Wobj    = (const float*)d_in[6];
    const float* bobj    = (const float*)d_in[7];
    const float* Wrel    = (const float*)d_in[8];
    const float* brel    = (const float*)d_in[9];
    const float* Wo      = (const float*)d_in[10];
    const float* bo      = (const float*)d_in[11];
    const float* Wa      = (const float*)d_in[12];
    const float* ba      = (const float*)d_in[13];

    float* out0 = (float*)d_out;
    float* out1 = out0 + (size_t)NB * 3072 * 512;   // 50331648 floats

    char* w = (char*)d_ws;
    ushort* EB   = (ushort*)w; w += (size_t)VOCAB * D * 2;            //  2.0 MB
    ushort* WT   = (ushort*)w; w += (size_t)12 * WT_BLK * 2;          //  6.3 MB
    float*  PRE  = (float*) w; w += (size_t)9 * PRE_BLK * 4;          // 37.7 MB
    ushort* feat = (ushort*)w; w += (size_t)M_ROWS * 1024 * 2;        // 67.1 MB  [sbjf | objf]
    float*  node = (float*) w; w += (size_t)M_ROWS * D * 4;           // 67.1 MB

    // 1) converts / transposes
    k_cvt_emb<<<dim3(VOCAB * D / 1024), dim3(256), 0, stream>>>(emb, EB);
    k_transpose_w<<<dim3(16, 16, 12), dim3(32, 8), 0, stream>>>(Wsbj, Wobj, Wrel, Wo, Wa, WT);
    // 2) PRE = E @ {9 weight blocks}
    k_gemm<0><<<dim3(16, 4, 9), dim3(256), 0, stream>>>(EB, WT, PRE, ssg_rel, ssg_obj,
                                                        nullptr, nullptr, nullptr, nullptr);
    // 3) node init (needs PRE q6)
    k_node_init<<<dim3(M_ROWS / 2), dim3(256), 0, stream>>>(ssg_obj, PRE, bo, node);
    // 4) sbj_f lookup layer + scatter -> feat lo-half
    k_sbj<<<dim3(M_ROWS / 2), dim3(256), 0, stream>>>(ssg_rel, ssg_obj, PRE, bsbj, feat, node);
    // 5) obj_f = sbjf @ Wobj0 (+gathers) -> feat hi-half + node atomics
    k_gemm<1><<<dim3(4, M_ROWS / 128), dim3(256), 0, stream>>>(feat, WT, PRE, ssg_rel, ssg_obj,
                                                               bobj, feat, node, nullptr);
    // 6) rel_f = [sbjf|objf] @ [Wrel0;Wrel1] (+gathers) -> out0 (f32)
    k_gemm<2><<<dim3(4, M_ROWS / 128), dim3(256), 0, stream>>>(feat, WT, PRE, ssg_rel, ssg_obj,
                                                               brel, nullptr, nullptr, out0);
    // 7) rel_object_feat = node / 2048 -> out0
    k_node_out<<<dim3(M_ROWS * D / 1024), dim3(256), 0, stream>>>(node, out0);
    // 8) attribute features -> out0
    k_att<<<dim3(M_ROWS / 2), dim3(256), 0, stream>>>(ssg_obj, ssg_att, PRE, ba, out0);
    // 9) masks -> out1
    k_mask<<<dim3((NB * 3072 + 255) / 256), dim3(256), 0, stream>>>(ssg_rel, ssg_obj, ssg_att, out1);
}

// Round 4
// 272.162 us; speedup vs baseline: 1.7742x; 1.7742x over previous
//
#include <hip/hip_runtime.h>
#include <hip/hip_bf16.h>

typedef __attribute__((ext_vector_type(8))) short bf16x8;
typedef __attribute__((ext_vector_type(4))) float f32x4;

#define N_OBJ 1024
#define N_REL 1024
#define NB 32
#define D 512
#define VOCAB 2048
#define M_ROWS (NB * N_REL)          // 32768
#define PRE_BLK (VOCAB * D)          // 1048576 floats per PRE block
#define WT_BLK (D * D)               // 262144 elems per transposed weight block

__device__ __forceinline__ ushort f2bf(float f) {
    union { float f; unsigned u; } v; v.f = f;
    unsigned u = v.u;
    unsigned r = (u + 0x7FFFu + ((u >> 16) & 1u)) >> 16;
    return (ushort)r;
}
__device__ __forceinline__ float bf2f(ushort h) {
    union { unsigned u; float f; } v; v.u = ((unsigned)h) << 16;
    return v.f;
}

// global -> LDS async 16B copy (m97 pattern; dest wave-uniform base + lane*16)
__device__ __forceinline__ void gload16(const ushort* g, const ushort* l) {
    __builtin_amdgcn_global_load_lds(
        (const __attribute__((address_space(1))) void*)(unsigned long long)(const void*)g,
        (__attribute__((address_space(3))) void*)(unsigned)(unsigned long long)(const void*)l,
        16, 0, 0);
}

// ---------------- K0a: emb_table f32 -> bf16 (float4) ----------------
__global__ void k_cvt_emb(const float* __restrict__ E, ushort* __restrict__ EB) {
    int i = blockIdx.x * 256 + threadIdx.x;   // over 262144 float4 groups
    float4 v = ((const float4*)E)[i];
    ushort4 o; o.x = f2bf(v.x); o.y = f2bf(v.y); o.z = f2bf(v.z); o.w = f2bf(v.w);
    ((ushort4*)EB)[i] = o;
}

// ---------------- K0b: transpose weight 512x512 blocks to N x K bf16 ----------------
// WT order: 0,1,2 = W_sbj k-blocks; 3,4,5 = W_obj; 6,7,8 = W_rel; 9 = W_o; 10,11 = W_a
__global__ void k_transpose_w(const float* __restrict__ Wsbj, const float* __restrict__ Wobj,
                              const float* __restrict__ Wrel, const float* __restrict__ Wo,
                              const float* __restrict__ Wa, ushort* __restrict__ WT) {
    __shared__ float s[32][33];
    int q = blockIdx.z;
    const float* src; int ro;
    if (q < 3)       { src = Wsbj; ro = q * 512; }
    else if (q < 6)  { src = Wobj; ro = (q - 3) * 512; }
    else if (q < 9)  { src = Wrel; ro = (q - 6) * 512; }
    else if (q == 9) { src = Wo;   ro = 0; }
    else             { src = Wa;   ro = (q - 10) * 512; }
    int tx = threadIdx.x, ty = threadIdx.y;        // 32 x 8
    int kbase = blockIdx.y * 32, nbase = blockIdx.x * 32;
#pragma unroll
    for (int i = 0; i < 4; i++) {
        int k = kbase + ty + i * 8;
        s[ty + i * 8][tx] = src[(size_t)(ro + k) * 512 + nbase + tx];
    }
    __syncthreads();
    ushort* dst = WT + (size_t)q * WT_BLK;
#pragma unroll
    for (int i = 0; i < 4; i++) {
        int n = nbase + ty + i * 8;
        dst[(size_t)n * 512 + kbase + tx] = f2bf(s[tx][ty + i * 8]);
    }
}

// ---------------- GEMM: 128x128 tile, BK=64, global_load_lds ----------------
// MODE 0: PRE = EB @ WT[q]        grid (16,4,9), K=512, lda=512
// MODE 1: obj_f = sbjf @ Wobj0    grid (4,256),  K=512, lda=1024 -> featbuf hi (no atomics)
// MODE 2: rel_f = [sbjf|objf] @ [Wrel0;Wrel1]  grid (4,256), K=1024 -> out0 (f32)
template <int MODE>
__global__ __launch_bounds__(256)
void k_gemm(const ushort* __restrict__ A, const ushort* __restrict__ WT,
            float* __restrict__ PRE,
            const int* __restrict__ ssg_rel, const int* __restrict__ ssg_obj,
            const float* __restrict__ bias,
            ushort* __restrict__ featbuf, float* __restrict__ out0) {
    __shared__ __attribute__((aligned(16))) ushort sA[128 * 64];
    __shared__ __attribute__((aligned(16))) ushort sB[128 * 64];

    const int tid = threadIdx.x;
    int mt, nt;
    if (MODE == 0) { mt = blockIdx.x; nt = blockIdx.y; }
    else {
        // XCD-chunked swizzle: co-locate the 4 nt-blocks of consecutive mt on one XCD
        int bid = blockIdx.y * 4 + blockIdx.x;           // 0..1023
        int nb = (bid & 7) * 128 + (bid >> 3);           // bijective (1024 % 8 == 0)
        mt = nb >> 2; nt = nb & 3;
    }
    const int m0 = mt * 128;
    constexpr int LDA = (MODE == 0) ? 512 : 1024;
    constexpr int KTOT = (MODE == 2) ? 1024 : 512;

    const ushort* BT0;
    const ushort* BT1 = nullptr;
    float* PREq = nullptr;
    if (MODE == 0) {
        const int wtq[9] = {0, 1, 2, 4, 5, 8, 9, 10, 11};
        int q = blockIdx.z;
        if ((q == 2 || q == 4 || q == 5) && mt >= 8) return;  // rid-only blocks: rows<1024
        BT0 = WT + (size_t)wtq[q] * WT_BLK + (size_t)nt * 128 * 512;
        PREq = PRE + (size_t)q * PRE_BLK;
    } else if (MODE == 1) {
        BT0 = WT + (size_t)3 * WT_BLK + (size_t)nt * 128 * 512;
    } else {
        BT0 = WT + (size_t)6 * WT_BLK + (size_t)nt * 128 * 512;
        BT1 = WT + (size_t)7 * WT_BLK + (size_t)nt * 128 * 512;
    }

    const int wave = tid >> 6;
    const int wm = wave >> 1, wn = wave & 1;
    const int lr = tid & 15, lk = (tid & 63) >> 4;

    f32x4 acc[4][4];
#pragma unroll
    for (int mi = 0; mi < 4; mi++)
#pragma unroll
        for (int ni = 0; ni < 4; ni++)
            acc[mi][ni] = (f32x4){0.f, 0.f, 0.f, 0.f};

    const ushort* Ag = A + (size_t)m0 * LDA;
    const int srow = tid >> 3;            // 0..31
    const int scol = (tid & 7) * 8;       // 0..56

    for (int k0 = 0; k0 < KTOT; k0 += 64) {
        const ushort* As = Ag + (size_t)srow * LDA + k0 + scol;
        const ushort* Bbase = (MODE == 2 && k0 >= 512) ? (BT1 + (k0 - 512)) : (BT0 + k0);
        const ushort* Bs = Bbase + (size_t)srow * 512 + scol;
#pragma unroll
        for (int i = 0; i < 4; i++)
            gload16(As + (size_t)i * 32 * LDA, &sA[i * 2048 + tid * 8]);
#pragma unroll
        for (int i = 0; i < 4; i++)
            gload16(Bs + (size_t)i * 32 * 512, &sB[i * 2048 + tid * 8]);
        __syncthreads();
#pragma unroll
        for (int ks = 0; ks < 2; ks++) {
            bf16x8 af[4], bfr[4];
#pragma unroll
            for (int mi = 0; mi < 4; mi++)
                af[mi] = *(const bf16x8*)&sA[(wm * 64 + mi * 16 + lr) * 64 + ks * 32 + lk * 8];
#pragma unroll
            for (int ni = 0; ni < 4; ni++)
                bfr[ni] = *(const bf16x8*)&sB[(wn * 64 + ni * 16 + lr) * 64 + ks * 32 + lk * 8];
#pragma unroll
            for (int mi = 0; mi < 4; mi++)
#pragma unroll
                for (int ni = 0; ni < 4; ni++)
                    acc[mi][ni] = __builtin_amdgcn_mfma_f32_16x16x32_bf16(af[mi], bfr[ni], acc[mi][ni], 0, 0, 0);
        }
        __syncthreads();
    }

    // ---- epilogue ----
    int* sIo  = (int*)sA;
    int* sRid = sIo + 128;
    if (MODE == 1 || MODE == 2) {
        if (tid < 128) {
            int R = m0 + tid;
            sRid[tid] = ssg_rel[R * 3 + 2];
            if (MODE == 1) sIo[tid] = ssg_obj[(R & ~(N_OBJ - 1)) + ssg_rel[R * 3 + 1]];
        }
        __syncthreads();
    }

#pragma unroll
    for (int mi = 0; mi < 4; mi++) {
#pragma unroll
        for (int ni = 0; ni < 4; ni++) {
            int c = wn * 64 + ni * 16 + lr;
            int ch = nt * 128 + c;
#pragma unroll
            for (int j = 0; j < 4; j++) {
                int rl = wm * 64 + mi * 16 + lk * 4 + j;
                int R = m0 + rl;
                float v = acc[mi][ni][j];
                if (MODE == 0) {
                    PREq[(size_t)R * 512 + ch] = v;
                } else if (MODE == 1) {
                    int rid = sRid[rl];
                    int io = sIo[rl];
                    float t = v + PRE[(size_t)3 * PRE_BLK + (size_t)io * 512 + ch]
                                + PRE[(size_t)4 * PRE_BLK + (size_t)rid * 512 + ch]
                                + bias[ch];
                    t = fmaxf(t, 0.f);
                    if (rid == 1) t = 0.f;
                    featbuf[(size_t)R * 1024 + 512 + ch] = f2bf(t);
                } else {  // MODE 2
                    int rid = sRid[rl];
                    float t = v + PRE[(size_t)5 * PRE_BLK + (size_t)rid * 512 + ch]
                                + bias[ch];
                    t = fmaxf(t, 0.f);
                    if (rid == 1) t = 0.f;
                    int b = R >> 10, rr = R & (N_REL - 1);
                    out0[((size_t)(b * 3072 + 1024 + rr)) * 512 + ch] = t;
                }
            }
        }
    }
}

// ---------------- sbj_f: table lookup layer (no atomics) ----------------
__global__ void k_sbj(const int* __restrict__ ssg_rel, const int* __restrict__ ssg_obj,
                      const float* __restrict__ PRE, const float* __restrict__ b_sbj,
                      ushort* __restrict__ featbuf) {
    int R = blockIdx.x * 2 + (threadIdx.x >> 7);
    int c4 = threadIdx.x & 127;
    int sid = ssg_rel[R * 3 + 0];
    int oid = ssg_rel[R * 3 + 1];
    int rid = ssg_rel[R * 3 + 2];
    int bb = R & ~(N_OBJ - 1);
    int is_ = ssg_obj[bb + sid];
    int io  = ssg_obj[bb + oid];
    float4 p1 = ((const float4*)(PRE + (size_t)is_ * 512))[c4];
    float4 p2 = ((const float4*)(PRE + (size_t)1 * PRE_BLK + (size_t)io * 512))[c4];
    float4 p3 = ((const float4*)(PRE + (size_t)2 * PRE_BLK + (size_t)rid * 512))[c4];
    float4 b  = ((const float4*)b_sbj)[c4];
    float4 v;
    v.x = fmaxf(p1.x + p2.x + p3.x + b.x, 0.f);
    v.y = fmaxf(p1.y + p2.y + p3.y + b.y, 0.f);
    v.z = fmaxf(p1.z + p2.z + p3.z + b.z, 0.f);
    v.w = fmaxf(p1.w + p2.w + p3.w + b.w, 0.f);
    if (rid == 1) { v.x = v.y = v.z = v.w = 0.f; }
    ushort4 o; o.x = f2bf(v.x); o.y = f2bf(v.y); o.z = f2bf(v.z); o.w = f2bf(v.w);
    *(ushort4*)&featbuf[(size_t)R * 1024 + c4 * 4] = o;
}

// ---------------- CSR build: count -> scan -> fill ----------------
__global__ void k_zero(int* __restrict__ p) {
    p[blockIdx.x * 256 + threadIdx.x] = 0;
}
__global__ void k_csr_count(const int* __restrict__ ssg_rel, int* __restrict__ cnt) {
    int r = blockIdx.x * 256 + threadIdx.x;      // 0..32767
    int bb = r & ~(N_OBJ - 1);
    atomicAdd(&cnt[bb + ssg_rel[r * 3 + 0]], 1);
    atomicAdd(&cnt[bb + ssg_rel[r * 3 + 1]], 1);
}
__global__ __launch_bounds__(1024)
void k_csr_scan(const int* __restrict__ cnt, int* __restrict__ offs, int* __restrict__ cursor) {
    __shared__ int part[1024];
    int t = threadIdx.x;
    int base = t * 32;
    int local[32];
    int sum = 0;
#pragma unroll
    for (int i = 0; i < 32; i++) { local[i] = sum; sum += cnt[base + i]; }
    part[t] = sum;
    __syncthreads();
    for (int d = 1; d < 1024; d <<= 1) {
        int v = (t >= d) ? part[t - d] : 0;
        __syncthreads();
        part[t] += v;
        __syncthreads();
    }
    int excl = (t == 0) ? 0 : part[t - 1];
#pragma unroll
    for (int i = 0; i < 32; i++) {
        int o = excl + local[i];
        offs[base + i] = o;
        cursor[base + i] = o;
    }
    if (t == 1023) offs[32768] = part[1023];
}
__global__ void k_csr_fill(const int* __restrict__ ssg_rel, int* __restrict__ cursor,
                           int* __restrict__ lists) {
    int r = blockIdx.x * 256 + threadIdx.x;
    int bb = r & ~(N_OBJ - 1);
    int p0 = atomicAdd(&cursor[bb + ssg_rel[r * 3 + 0]], 1);
    lists[p0] = r * 2;
    int p1 = atomicAdd(&cursor[bb + ssg_rel[r * 3 + 1]], 1);
    lists[p1] = r * 2 + 1;
}

// ---------------- node gather-reduce -> out0 lo section ----------------
__global__ void k_node_gather(const int* __restrict__ ssg_obj, const int* __restrict__ offs,
                              const int* __restrict__ lists, const ushort* __restrict__ feat,
                              const float* __restrict__ PRE, const float* __restrict__ b_o,
                              float* __restrict__ out0) {
    int Ro = blockIdx.x;                         // 0..32767 = b*1024+o
    int t = threadIdx.x;                         // 256: 2 floats each
    int iv = ssg_obj[Ro];
    float2 b = ((const float2*)b_o)[t];
    float2 q = ((const float2*)(PRE + (size_t)6 * PRE_BLK + (size_t)iv * 512))[t];
    float a0 = 0.f, a1 = 0.f;
    if (iv != 1) {
        a0 = fmaxf(q.x + b.x, 0.f);
        a1 = fmaxf(q.y + b.y, 0.f);
    }
    int s = offs[Ro], e = offs[Ro + 1];
    for (int i = s; i < e; ++i) {
        int ent = lists[i];
        const ushort* row = feat + (size_t)(ent >> 1) * 1024 + (ent & 1) * 512;
        ushort2 u = ((const ushort2*)row)[t];
        a0 += bf2f(u.x);
        a1 += bf2f(u.y);
    }
    int bq = Ro >> 10, o = Ro & (N_OBJ - 1);
    float2 r; r.x = a0 * (1.0f / 2048.0f); r.y = a1 * (1.0f / 2048.0f);
    ((float2*)out0)[((size_t)(bq * 3072 + o)) * 256 + t] = r;
}

// ---------------- att features (float4) ----------------
__global__ void k_att(const int* __restrict__ ssg_obj, const int* __restrict__ ssg_att,
                      const float* __restrict__ PRE, const float* __restrict__ b_a,
                      float* __restrict__ out0) {
    int Ro = blockIdx.x * 2 + (threadIdx.x >> 7);
    int c4 = threadIdx.x & 127;
    int iv = ssg_obj[Ro];
    int j0 = ssg_att[Ro * 4 + 0], j1 = ssg_att[Ro * 4 + 1];
    int j2 = ssg_att[Ro * 4 + 2], j3 = ssg_att[Ro * 4 + 3];
    const float4* A2 = (const float4*)(PRE + (size_t)8 * PRE_BLK);
    float4 a1 = ((const float4*)(PRE + (size_t)7 * PRE_BLK + (size_t)iv * 512))[c4];
    float4 ba = ((const float4*)b_a)[c4];
    float4 base;
    base.x = a1.x + ba.x; base.y = a1.y + ba.y; base.z = a1.z + ba.z; base.w = a1.w + ba.w;
    int cnt = (j0 != 1) + (j1 != 1) + (j2 != 1) + (j3 != 1);
    float inv = cnt ? 1.0f / (float)cnt : 0.f;
    float4 s = {0.f, 0.f, 0.f, 0.f};
#define ACC_ATT(J) if ((J) != 1) { \
        float4 a2 = A2[(size_t)(J) * 128 + c4]; \
        s.x += fmaxf(base.x + a2.x, 0.f); s.y += fmaxf(base.y + a2.y, 0.f); \
        s.z += fmaxf(base.z + a2.z, 0.f); s.w += fmaxf(base.w + a2.w, 0.f); }
    ACC_ATT(j0) ACC_ATT(j1) ACC_ATT(j2) ACC_ATT(j3)
#undef ACC_ATT
    s.x *= inv; s.y *= inv; s.z *= inv; s.w *= inv;
    int b = Ro >> 10, o = Ro & (N_OBJ - 1);
    ((float4*)out0)[((size_t)(b * 3072 + 2048 + o)) * 128 + c4] = s;
}

// ---------------- masks ----------------
__global__ void k_mask(const int* __restrict__ ssg_rel, const int* __restrict__ ssg_obj,
                       const int* __restrict__ ssg_att, float* __restrict__ out1) {
    int i = blockIdx.x * 256 + threadIdx.x;
    if (i >= NB * 3072) return;
    int b = i / 3072, j = i % 3072;
    bool m;
    if (j < 1024) m = (ssg_obj[b * 1024 + j] == 1);
    else if (j < 2048) m = (ssg_rel[(b * 1024 + (j - 1024)) * 3 + 2] == 1);
    else {
        const int* p = ssg_att + (size_t)(b * 1024 + (j - 2048)) * 4;
        m = (p[0] == 1) && (p[1] == 1) && (p[2] == 1) && (p[3] == 1);
    }
    out1[i] = m ? 1.0f : 0.0f;
}

extern "C" void kernel_launch(void* const* d_in, const int* in_sizes, int n_in,
                              void* d_out, int out_size, void* d_ws, size_t ws_size,
                              hipStream_t stream) {
    const int*   ssg_rel = (const int*)d_in[0];
    const int*   ssg_obj = (const int*)d_in[1];
    const int*   ssg_att = (const int*)d_in[2];
    const float* emb     = (const float*)d_in[3];
    const float* Wsbj    = (const float*)d_in[4];
    const float* bsbj    = (const float*)d_in[5];
    const float* Wobj    = (const float*)d_in[6];
    const float* bobj    = (const float*)d_in[7];
    const float* Wrel    = (const float*)d_in[8];
    const float* brel    = (const float*)d_in[9];
    const float* Wo      = (const float*)d_in[10];
    const float* bo      = (const float*)d_in[11];
    const float* Wa      = (const float*)d_in[12];
    const float* ba      = (const float*)d_in[13];

    float* out0 = (float*)d_out;
    float* out1 = out0 + (size_t)NB * 3072 * 512;

    char* w = (char*)d_ws;
    ushort* EB     = (ushort*)w; w += (size_t)VOCAB * D * 2;          //  2.0 MB
    ushort* WT     = (ushort*)w; w += (size_t)12 * WT_BLK * 2;        //  6.3 MB
    float*  PRE    = (float*) w; w += (size_t)9 * PRE_BLK * 4;        // 37.7 MB
    ushort* feat   = (ushort*)w; w += (size_t)M_ROWS * 1024 * 2;      // 67.1 MB  [sbjf | objf]
    int*    cnt    = (int*)   w; w += (size_t)32768 * 4;
    int*    offs   = (int*)   w; w += (size_t)32769 * 4;
    int*    cursor = (int*)   w; w += (size_t)32768 * 4;
    int*    lists  = (int*)   w; w += (size_t)65536 * 4;

    // 1) converts / transposes
    k_cvt_emb<<<dim3(VOCAB * D / 1024), dim3(256), 0, stream>>>(emb, EB);
    k_transpose_w<<<dim3(16, 16, 12), dim3(32, 8), 0, stream>>>(Wsbj, Wobj, Wrel, Wo, Wa, WT);
    // 2) CSR inverted index (independent of PRE)
    k_zero<<<dim3(128), dim3(256), 0, stream>>>(cnt);
    k_csr_count<<<dim3(128), dim3(256), 0, stream>>>(ssg_rel, cnt);
    k_csr_scan<<<dim3(1), dim3(1024), 0, stream>>>(cnt, offs, cursor);
    k_csr_fill<<<dim3(128), dim3(256), 0, stream>>>(ssg_rel, cursor, lists);
    // 3) PRE = E @ {9 weight blocks}
    k_gemm<0><<<dim3(16, 4, 9), dim3(256), 0, stream>>>(EB, WT, PRE, ssg_rel, ssg_obj,
                                                        nullptr, nullptr, nullptr);
    // 4) sbj_f lookup layer -> feat lo (no atomics)
    k_sbj<<<dim3(M_ROWS / 2), dim3(256), 0, stream>>>(ssg_rel, ssg_obj, PRE, bsbj, feat);
    // 5) obj_f = sbjf @ Wobj0 (+gathers) -> feat hi (no atomics)
    k_gemm<1><<<dim3(4, M_ROWS / 128), dim3(256), 0, stream>>>(feat, WT, PRE, ssg_rel, ssg_obj,
                                                               bobj, feat, nullptr);
    // 6) rel_f = [sbjf|objf] @ [Wrel0;Wrel1] (+gathers) -> out0 (f32)
    k_gemm<2><<<dim3(4, M_ROWS / 128), dim3(256), 0, stream>>>(feat, WT, PRE, ssg_rel, ssg_obj,
                                                               brel, nullptr, out0);
    // 7) node = init + CSR gather-reduce; /2048 -> out0 lo
    k_node_gather<<<dim3(M_ROWS), dim3(256), 0, stream>>>(ssg_obj, offs, lists, feat, PRE, bo, out0);
    // 8) attribute features -> out0 hi
    k_att<<<dim3(M_ROWS / 2), dim3(256), 0, stream>>>(ssg_obj, ssg_att, PRE, ba, out0);
    // 9) masks -> out1
    k_mask<<<dim3((NB * 3072 + 255) / 256), dim3(256), 0, stream>>>(ssg_rel, ssg_obj, ssg_att, out1);
}

// Round 5
// 237.606 us; speedup vs baseline: 2.0322x; 1.1454x over previous
//
#include <hip/hip_runtime.h>
#include <hip/hip_bf16.h>

typedef __attribute__((ext_vector_type(8))) short bf16x8;
typedef __attribute__((ext_vector_type(4))) float f32x4;

#define N_OBJ 1024
#define N_REL 1024
#define NB 32
#define D 512
#define VOCAB 2048
#define M_ROWS (NB * N_REL)          // 32768
#define PRE_BLK (VOCAB * D)          // 1048576 elems per PRE block (bf16)
#define WT_BLK (D * D)               // 262144 elems per transposed weight block

__device__ __forceinline__ ushort f2bf(float f) {
    union { float f; unsigned u; } v; v.f = f;
    unsigned u = v.u;
    unsigned r = (u + 0x7FFFu + ((u >> 16) & 1u)) >> 16;
    return (ushort)r;
}
__device__ __forceinline__ float bf2f(ushort h) {
    union { unsigned u; float f; } v; v.u = ((unsigned)h) << 16;
    return v.f;
}

// global -> LDS async 16B copy (m97 pattern; dest wave-uniform base + lane*16)
__device__ __forceinline__ void gload16(const ushort* g, const ushort* l) {
    __builtin_amdgcn_global_load_lds(
        (const __attribute__((address_space(1))) void*)(unsigned long long)(const void*)g,
        (__attribute__((address_space(3))) void*)(unsigned)(unsigned long long)(const void*)l,
        16, 0, 0);
}

// ---------------- K0a: emb_table f32 -> bf16 (float4) ----------------
__global__ void k_cvt_emb(const float* __restrict__ E, ushort* __restrict__ EB) {
    int i = blockIdx.x * 256 + threadIdx.x;   // over 262144 float4 groups
    float4 v = ((const float4*)E)[i];
    ushort4 o; o.x = f2bf(v.x); o.y = f2bf(v.y); o.z = f2bf(v.z); o.w = f2bf(v.w);
    ((ushort4*)EB)[i] = o;
}

// ---------------- K0b: transpose weight 512x512 blocks to N x K bf16 ----------------
// WT order: 0,1,2 = W_sbj k-blocks; 3,4,5 = W_obj; 6,7,8 = W_rel; 9 = W_o; 10,11 = W_a
__global__ void k_transpose_w(const float* __restrict__ Wsbj, const float* __restrict__ Wobj,
                              const float* __restrict__ Wrel, const float* __restrict__ Wo,
                              const float* __restrict__ Wa, ushort* __restrict__ WT) {
    __shared__ float s[32][33];
    int q = blockIdx.z;
    const float* src; int ro;
    if (q < 3)       { src = Wsbj; ro = q * 512; }
    else if (q < 6)  { src = Wobj; ro = (q - 3) * 512; }
    else if (q < 9)  { src = Wrel; ro = (q - 6) * 512; }
    else if (q == 9) { src = Wo;   ro = 0; }
    else             { src = Wa;   ro = (q - 10) * 512; }
    int tx = threadIdx.x, ty = threadIdx.y;        // 32 x 8
    int kbase = blockIdx.y * 32, nbase = blockIdx.x * 32;
#pragma unroll
    for (int i = 0; i < 4; i++) {
        int k = kbase + ty + i * 8;
        s[ty + i * 8][tx] = src[(size_t)(ro + k) * 512 + nbase + tx];
    }
    __syncthreads();
    ushort* dst = WT + (size_t)q * WT_BLK;
#pragma unroll
    for (int i = 0; i < 4; i++) {
        int n = nbase + ty + i * 8;
        dst[(size_t)n * 512 + kbase + tx] = f2bf(s[tx][ty + i * 8]);
    }
}

// ---------------- GEMM: 128x128 tile, BK=64, global_load_lds ----------------
// MODE 0: PREB = EB @ WT[q] (bf16 out)   grid (16,4,9), K=512, lda=512
// MODE 1: obj_f = sbjf @ Wobj0           grid (4,256),  K=512, lda=1024 -> featbuf hi
// MODE 2: rel_f = [sbjf|objf] @ [Wrel0;Wrel1]  grid (4,256), K=1024 -> out0 + rel mask
template <int MODE>
__global__ __launch_bounds__(256)
void k_gemm(const ushort* __restrict__ A, const ushort* __restrict__ WT,
            ushort* __restrict__ PREB,
            const int* __restrict__ ssg_rel, const int* __restrict__ ssg_obj,
            const float* __restrict__ bias,
            ushort* __restrict__ featbuf, float* __restrict__ out0,
            float* __restrict__ out1) {
    __shared__ __attribute__((aligned(16))) ushort sA[128 * 64];
    __shared__ __attribute__((aligned(16))) ushort sB[128 * 64];

    const int tid = threadIdx.x;
    int mt, nt;
    if (MODE == 0) { mt = blockIdx.x; nt = blockIdx.y; }
    else {
        // XCD-chunked swizzle: co-locate the 4 nt-blocks of consecutive mt on one XCD
        int bid = blockIdx.y * 4 + blockIdx.x;           // 0..1023
        int nb = (bid & 7) * 128 + (bid >> 3);           // bijective (1024 % 8 == 0)
        mt = nb >> 2; nt = nb & 3;
    }
    const int m0 = mt * 128;
    constexpr int LDA = (MODE == 0) ? 512 : 1024;
    constexpr int KTOT = (MODE == 2) ? 1024 : 512;

    const ushort* BT0;
    const ushort* BT1 = nullptr;
    ushort* PREq = nullptr;
    if (MODE == 0) {
        const int wtq[9] = {0, 1, 2, 4, 5, 8, 9, 10, 11};
        int q = blockIdx.z;
        if ((q == 2 || q == 4 || q == 5) && mt >= 8) return;  // rid-indexed blocks: rows<1024
        BT0 = WT + (size_t)wtq[q] * WT_BLK + (size_t)nt * 128 * 512;
        PREq = PREB + (size_t)q * PRE_BLK;
    } else if (MODE == 1) {
        BT0 = WT + (size_t)3 * WT_BLK + (size_t)nt * 128 * 512;
    } else {
        BT0 = WT + (size_t)6 * WT_BLK + (size_t)nt * 128 * 512;
        BT1 = WT + (size_t)7 * WT_BLK + (size_t)nt * 128 * 512;
    }

    const int wave = tid >> 6;
    const int wm = wave >> 1, wn = wave & 1;
    const int lr = tid & 15, lk = (tid & 63) >> 4;

    f32x4 acc[4][4];
#pragma unroll
    for (int mi = 0; mi < 4; mi++)
#pragma unroll
        for (int ni = 0; ni < 4; ni++)
            acc[mi][ni] = (f32x4){0.f, 0.f, 0.f, 0.f};

    const ushort* Ag = A + (size_t)m0 * LDA;
    const int srow = tid >> 3;            // 0..31
    const int scol = (tid & 7) * 8;       // 0..56

    for (int k0 = 0; k0 < KTOT; k0 += 64) {
        const ushort* As = Ag + (size_t)srow * LDA + k0 + scol;
        const ushort* Bbase = (MODE == 2 && k0 >= 512) ? (BT1 + (k0 - 512)) : (BT0 + k0);
        const ushort* Bs = Bbase + (size_t)srow * 512 + scol;
#pragma unroll
        for (int i = 0; i < 4; i++)
            gload16(As + (size_t)i * 32 * LDA, &sA[i * 2048 + tid * 8]);
#pragma unroll
        for (int i = 0; i < 4; i++)
            gload16(Bs + (size_t)i * 32 * 512, &sB[i * 2048 + tid * 8]);
        __syncthreads();
#pragma unroll
        for (int ks = 0; ks < 2; ks++) {
            bf16x8 af[4], bfr[4];
#pragma unroll
            for (int mi = 0; mi < 4; mi++)
                af[mi] = *(const bf16x8*)&sA[(wm * 64 + mi * 16 + lr) * 64 + ks * 32 + lk * 8];
#pragma unroll
            for (int ni = 0; ni < 4; ni++)
                bfr[ni] = *(const bf16x8*)&sB[(wn * 64 + ni * 16 + lr) * 64 + ks * 32 + lk * 8];
#pragma unroll
            for (int mi = 0; mi < 4; mi++)
#pragma unroll
                for (int ni = 0; ni < 4; ni++)
                    acc[mi][ni] = __builtin_amdgcn_mfma_f32_16x16x32_bf16(af[mi], bfr[ni], acc[mi][ni], 0, 0, 0);
        }
        __syncthreads();
    }

    // ---- epilogue ----
    int* sIo  = (int*)sA;
    int* sRid = sIo + 128;
    if (MODE == 1 || MODE == 2) {
        if (tid < 128) {
            int R = m0 + tid;
            int rid = ssg_rel[R * 3 + 2];
            sRid[tid] = rid;
            if (MODE == 1) sIo[tid] = ssg_obj[(R & ~(N_OBJ - 1)) + ssg_rel[R * 3 + 1]];
            if (MODE == 2 && nt == 0) {
                int b = R >> 10, rr = R & (N_REL - 1);
                out1[(size_t)b * 3072 + 1024 + rr] = (rid == 1) ? 1.0f : 0.0f;
            }
        }
        __syncthreads();
    }

#pragma unroll
    for (int mi = 0; mi < 4; mi++) {
#pragma unroll
        for (int ni = 0; ni < 4; ni++) {
            int c = wn * 64 + ni * 16 + lr;
            int ch = nt * 128 + c;
#pragma unroll
            for (int j = 0; j < 4; j++) {
                int rl = wm * 64 + mi * 16 + lk * 4 + j;
                int R = m0 + rl;
                float v = acc[mi][ni][j];
                if (MODE == 0) {
                    PREq[(size_t)R * 512 + ch] = f2bf(v);
                } else if (MODE == 1) {
                    int rid = sRid[rl];
                    int io = sIo[rl];
                    float t = v + bf2f(PREB[(size_t)3 * PRE_BLK + (size_t)io * 512 + ch])
                                + bf2f(PREB[(size_t)4 * PRE_BLK + (size_t)rid * 512 + ch])
                                + bias[ch];
                    t = fmaxf(t, 0.f);
                    if (rid == 1) t = 0.f;
                    featbuf[(size_t)R * 1024 + 512 + ch] = f2bf(t);
                } else {  // MODE 2
                    int rid = sRid[rl];
                    float t = v + bf2f(PREB[(size_t)5 * PRE_BLK + (size_t)rid * 512 + ch])
                                + bias[ch];
                    t = fmaxf(t, 0.f);
                    if (rid == 1) t = 0.f;
                    int b = R >> 10, rr = R & (N_REL - 1);
                    out0[((size_t)(b * 3072 + 1024 + rr)) * 512 + ch] = t;
                }
            }
        }
    }
}

// ---------------- sbj_f: table lookup layer (bf16 PRE, no atomics) ----------------
__global__ void k_sbj(const int* __restrict__ ssg_rel, const int* __restrict__ ssg_obj,
                      const ushort* __restrict__ PREB, const float* __restrict__ b_sbj,
                      ushort* __restrict__ featbuf) {
    int R = blockIdx.x * 2 + (threadIdx.x >> 7);
    int c4 = threadIdx.x & 127;
    int sid = ssg_rel[R * 3 + 0];
    int oid = ssg_rel[R * 3 + 1];
    int rid = ssg_rel[R * 3 + 2];
    int bb = R & ~(N_OBJ - 1);
    int is_ = ssg_obj[bb + sid];
    int io  = ssg_obj[bb + oid];
    ushort4 p1 = ((const ushort4*)(PREB + (size_t)is_ * 512))[c4];
    ushort4 p2 = ((const ushort4*)(PREB + (size_t)1 * PRE_BLK + (size_t)io * 512))[c4];
    ushort4 p3 = ((const ushort4*)(PREB + (size_t)2 * PRE_BLK + (size_t)rid * 512))[c4];
    float4 b  = ((const float4*)b_sbj)[c4];
    float4 v;
    v.x = fmaxf(bf2f(p1.x) + bf2f(p2.x) + bf2f(p3.x) + b.x, 0.f);
    v.y = fmaxf(bf2f(p1.y) + bf2f(p2.y) + bf2f(p3.y) + b.y, 0.f);
    v.z = fmaxf(bf2f(p1.z) + bf2f(p2.z) + bf2f(p3.z) + b.z, 0.f);
    v.w = fmaxf(bf2f(p1.w) + bf2f(p2.w) + bf2f(p3.w) + b.w, 0.f);
    if (rid == 1) { v.x = v.y = v.z = v.w = 0.f; }
    ushort4 o; o.x = f2bf(v.x); o.y = f2bf(v.y); o.z = f2bf(v.z); o.w = f2bf(v.w);
    *(ushort4*)&featbuf[(size_t)R * 1024 + c4 * 4] = o;
}

// ---------------- CSR build: count -> scan -> fill ----------------
__global__ void k_zero(int* __restrict__ p) {
    p[blockIdx.x * 256 + threadIdx.x] = 0;
}
__global__ void k_csr_count(const int* __restrict__ ssg_rel, int* __restrict__ cnt) {
    int r = blockIdx.x * 256 + threadIdx.x;      // 0..32767
    int bb = r & ~(N_OBJ - 1);
    atomicAdd(&cnt[bb + ssg_rel[r * 3 + 0]], 1);
    atomicAdd(&cnt[bb + ssg_rel[r * 3 + 1]], 1);
}
__global__ __launch_bounds__(1024)
void k_csr_scan(const int* __restrict__ cnt, int* __restrict__ offs, int* __restrict__ cursor) {
    __shared__ int part[1024];
    int t = threadIdx.x;
    int base = t * 32;
    int local[32];
    int sum = 0;
#pragma unroll
    for (int i = 0; i < 32; i++) { local[i] = sum; sum += cnt[base + i]; }
    part[t] = sum;
    __syncthreads();
    for (int d = 1; d < 1024; d <<= 1) {
        int v = (t >= d) ? part[t - d] : 0;
        __syncthreads();
        part[t] += v;
        __syncthreads();
    }
    int excl = (t == 0) ? 0 : part[t - 1];
#pragma unroll
    for (int i = 0; i < 32; i++) {
        int o = excl + local[i];
        offs[base + i] = o;
        cursor[base + i] = o;
    }
    if (t == 1023) offs[32768] = part[1023];
}
__global__ void k_csr_fill(const int* __restrict__ ssg_rel, int* __restrict__ cursor,
                           int* __restrict__ lists) {
    int r = blockIdx.x * 256 + threadIdx.x;
    int bb = r & ~(N_OBJ - 1);
    int p0 = atomicAdd(&cursor[bb + ssg_rel[r * 3 + 0]], 1);
    lists[p0] = r * 2;
    int p1 = atomicAdd(&cursor[bb + ssg_rel[r * 3 + 1]], 1);
    lists[p1] = r * 2 + 1;
}

// ---------------- fused per-object pass: node gather + att features + masks --------
__global__ void k_objpass(const int* __restrict__ ssg_obj, const int* __restrict__ ssg_att,
                          const int* __restrict__ offs, const int* __restrict__ lists,
                          const ushort* __restrict__ feat, const ushort* __restrict__ PREB,
                          const float* __restrict__ b_o, const float* __restrict__ b_a,
                          float* __restrict__ out0, float* __restrict__ out1) {
    int Ro = blockIdx.x * 2 + (threadIdx.x >> 7);   // b*1024 + o
    int c4 = threadIdx.x & 127;                     // 4 channels each
    int iv = ssg_obj[Ro];
    int bq = Ro >> 10, o = Ro & (N_OBJ - 1);

    // --- node: init + CSR gather, /2048 ---
    float4 bo4 = ((const float4*)b_o)[c4];
    ushort4 q6 = ((const ushort4*)(PREB + (size_t)6 * PRE_BLK + (size_t)iv * 512))[c4];
    float a0 = 0.f, a1 = 0.f, a2 = 0.f, a3 = 0.f;
    if (iv != 1) {
        a0 = fmaxf(bf2f(q6.x) + bo4.x, 0.f);
        a1 = fmaxf(bf2f(q6.y) + bo4.y, 0.f);
        a2 = fmaxf(bf2f(q6.z) + bo4.z, 0.f);
        a3 = fmaxf(bf2f(q6.w) + bo4.w, 0.f);
    }
    int s = offs[Ro], e = offs[Ro + 1];
    for (int i = s; i < e; ++i) {
        int ent = lists[i];
        ushort4 u = ((const ushort4*)(feat + (size_t)(ent >> 1) * 1024 + (ent & 1) * 512))[c4];
        a0 += bf2f(u.x); a1 += bf2f(u.y); a2 += bf2f(u.z); a3 += bf2f(u.w);
    }
    float4 r;
    r.x = a0 * (1.0f / 2048.0f); r.y = a1 * (1.0f / 2048.0f);
    r.z = a2 * (1.0f / 2048.0f); r.w = a3 * (1.0f / 2048.0f);
    ((float4*)out0)[((size_t)(bq * 3072 + o)) * 128 + c4] = r;

    // --- att features ---
    int j0 = ssg_att[Ro * 4 + 0], j1 = ssg_att[Ro * 4 + 1];
    int j2 = ssg_att[Ro * 4 + 2], j3 = ssg_att[Ro * 4 + 3];
    float4 ba4 = ((const float4*)b_a)[c4];
    ushort4 q7 = ((const ushort4*)(PREB + (size_t)7 * PRE_BLK + (size_t)iv * 512))[c4];
    float bx = bf2f(q7.x) + ba4.x, by = bf2f(q7.y) + ba4.y;
    float bz = bf2f(q7.z) + ba4.z, bw = bf2f(q7.w) + ba4.w;
    int cnt = (j0 != 1) + (j1 != 1) + (j2 != 1) + (j3 != 1);
    float inv = cnt ? 1.0f / (float)cnt : 0.f;
    float sx = 0.f, sy = 0.f, sz = 0.f, sw = 0.f;
    const ushort* A2 = PREB + (size_t)8 * PRE_BLK;
#define ACC_ATT(J) if ((J) != 1) { \
        ushort4 a2 = ((const ushort4*)(A2 + (size_t)(J) * 512))[c4]; \
        sx += fmaxf(bx + bf2f(a2.x), 0.f); sy += fmaxf(by + bf2f(a2.y), 0.f); \
        sz += fmaxf(bz + bf2f(a2.z), 0.f); sw += fmaxf(bw + bf2f(a2.w), 0.f); }
    ACC_ATT(j0) ACC_ATT(j1) ACC_ATT(j2) ACC_ATT(j3)
#undef ACC_ATT
    float4 sv; sv.x = sx * inv; sv.y = sy * inv; sv.z = sz * inv; sv.w = sw * inv;
    ((float4*)out0)[((size_t)(bq * 3072 + 2048 + o)) * 128 + c4] = sv;

    // --- masks (obj + att sections) ---
    if (c4 == 0) {
        out1[(size_t)bq * 3072 + o] = (iv == 1) ? 1.0f : 0.0f;
        out1[(size_t)bq * 3072 + 2048 + o] = (cnt == 0) ? 1.0f : 0.0f;
    }
}

extern "C" void kernel_launch(void* const* d_in, const int* in_sizes, int n_in,
                              void* d_out, int out_size, void* d_ws, size_t ws_size,
                              hipStream_t stream) {
    const int*   ssg_rel = (const int*)d_in[0];
    const int*   ssg_obj = (const int*)d_in[1];
    const int*   ssg_att = (const int*)d_in[2];
    const float* emb     = (const float*)d_in[3];
    const float* Wsbj    = (const float*)d_in[4];
    const float* bsbj    = (const float*)d_in[5];
    const float* Wobj    = (const float*)d_in[6];
    const float* bobj    = (const float*)d_in[7];
    const float* Wrel    = (const float*)d_in[8];
    const float* brel    = (const float*)d_in[9];
    const float* Wo      = (const float*)d_in[10];
    const float* bo      = (const float*)d_in[11];
    const float* Wa      = (const float*)d_in[12];
    const float* ba      = (const float*)d_in[13];

    float* out0 = (float*)d_out;
    float* out1 = out0 + (size_t)NB * 3072 * 512;

    char* w = (char*)d_ws;
    ushort* EB     = (ushort*)w; w += (size_t)VOCAB * D * 2;          //  2.0 MB
    ushort* WT     = (ushort*)w; w += (size_t)12 * WT_BLK * 2;        //  6.3 MB
    ushort* PREB   = (ushort*)w; w += (size_t)9 * PRE_BLK * 2;        // 18.9 MB (bf16)
    ushort* feat   = (ushort*)w; w += (size_t)M_ROWS * 1024 * 2;      // 67.1 MB  [sbjf | objf]
    int*    cnt    = (int*)   w; w += (size_t)32768 * 4;
    int*    offs   = (int*)   w; w += (size_t)32769 * 4;
    int*    cursor = (int*)   w; w += (size_t)32768 * 4;
    int*    lists  = (int*)   w; w += (size_t)65536 * 4;

    // 1) converts / transposes
    k_cvt_emb<<<dim3(VOCAB * D / 1024), dim3(256), 0, stream>>>(emb, EB);
    k_transpose_w<<<dim3(16, 16, 12), dim3(32, 8), 0, stream>>>(Wsbj, Wobj, Wrel, Wo, Wa, WT);
    // 2) CSR inverted index (independent of PREB)
    k_zero<<<dim3(128), dim3(256), 0, stream>>>(cnt);
    k_csr_count<<<dim3(128), dim3(256), 0, stream>>>(ssg_rel, cnt);
    k_csr_scan<<<dim3(1), dim3(1024), 0, stream>>>(cnt, offs, cursor);
    k_csr_fill<<<dim3(128), dim3(256), 0, stream>>>(ssg_rel, cursor, lists);
    // 3) PREB = E @ {9 weight blocks} (bf16)
    k_gemm<0><<<dim3(16, 4, 9), dim3(256), 0, stream>>>(EB, WT, PREB, ssg_rel, ssg_obj,
                                                        nullptr, nullptr, nullptr, nullptr);
    // 4) sbj_f lookup layer -> feat lo
    k_sbj<<<dim3(M_ROWS / 2), dim3(256), 0, stream>>>(ssg_rel, ssg_obj, PREB, bsbj, feat);
    // 5) obj_f = sbjf @ Wobj0 (+gathers) -> feat hi
    k_gemm<1><<<dim3(4, M_ROWS / 128), dim3(256), 0, stream>>>(feat, WT, PREB, ssg_rel, ssg_obj,
                                                               bobj, feat, nullptr, nullptr);
    // 6) rel_f = [sbjf|objf] @ [Wrel0;Wrel1] (+gathers) -> out0 + rel mask
    k_gemm<2><<<dim3(4, M_ROWS / 128), dim3(256), 0, stream>>>(feat, WT, PREB, ssg_rel, ssg_obj,
                                                               brel, nullptr, out0, out1);
    // 7) fused per-object pass: node gather + att + obj/att masks
    k_objpass<<<dim3(M_ROWS / 2), dim3(256), 0, stream>>>(ssg_obj, ssg_att, offs, lists,
                                                          feat, PREB, bo, ba, out0, out1);
}